// Round 7
// baseline (46.931 us; speedup 1.0000x reference)
//
#include <hip/hip_runtime.h>

#ifndef NUM_CLASSES
#define NUM_CLASSES 10
#endif

// x: (B=64, TS=128, C=1, H=64, W=64) fp32 -> K = 4096
// Derivation: with F_THRESH=0, h_t == frame_{t-1} exactly, so
//   out[b,c] = ( sum_k Wfc[c,k] * S[b,k] + (TS-1)*bfc[c] ) / TS,
//   S[b,k]   = sum_{t=1..TS-1} sign3(x[b,t,k] - x[b,t-1,k])
// R7 (= R6 with compile fix): single kernel. Block (b,tc) streams 17 full
// 16KB frames = 272KB contiguous; FC fused per-thread; last-retiring block
// (atomic ticket) does the fixed-order final sum -> deterministic; second
// launch + graph gap deleted. x loads nontemporal (read-once, 128MB >> L2)
// via clang ext_vector_type (HIP float4 is rejected by the builtin).
constexpr int B_        = 64;
constexpr int TS_       = 128;
constexpr int K_        = 4096;
constexpr int THREADS_  = 512;
constexpr int TCHUNKS_  = 8;
constexpr int TSTEP_    = 16;                      // diffs per chunk (last: 15)
constexpr int NPART_    = TCHUNKS_;                // 8 partials per (b,c)
constexpr int NWAVES_   = THREADS_ / 64;           // 8
constexpr int NBLOCKS_  = B_ * TCHUNKS_;           // 512
constexpr int NTICKETS_ = NBLOCKS_ * NUM_CLASSES;  // one ticket per P write

typedef float f32x4 __attribute__((ext_vector_type(4)));

__device__ __forceinline__ f32x4 nt_load4(const float* p) {
    return __builtin_nontemporal_load(reinterpret_cast<const f32x4*>(p));
}

// Grid: (B_, TCHUNKS_) = 512 blocks, block: 512.
__global__ __launch_bounds__(THREADS_) void sign_fc_fused_kernel(
    const float* __restrict__ x, const float* __restrict__ Wfc,
    const float* __restrict__ bfc, float* __restrict__ out,
    float* __restrict__ P, unsigned int* __restrict__ cnt)
{
    const int b   = blockIdx.x;
    const int tc  = blockIdx.y;
    const int tid = threadIdx.x;

    __shared__ int sh_last;
    if (tid == 0) sh_last = 0;

    const int t_begin = tc * TSTEP_;
    const int t_end   = (tc == TCHUNKS_ - 1) ? (TS_ - 1) : (t_begin + TSTEP_);

    // Thread owns 8 k's: tid*4 + {0..3} and 2048 + tid*4 + {0..3}.
    const int kbase = tid * 4;

    const float* xp = x + ((size_t)b * TS_ + t_begin) * K_ + kbase;
    f32x4 prev0 = nt_load4(xp);
    f32x4 prev1 = nt_load4(xp + 2048);

    int s0 = 0, s1 = 0, s2 = 0, s3 = 0, s4 = 0, s5 = 0, s6 = 0, s7 = 0;

#pragma unroll 4
    for (int t = t_begin + 1; t <= t_end; ++t) {
        xp += K_;
        const f32x4 cur0 = nt_load4(xp);
        const f32x4 cur1 = nt_load4(xp + 2048);
        float d;
        d = cur0.x - prev0.x; s0 += (d > 0.0f) - (d < 0.0f);
        d = cur0.y - prev0.y; s1 += (d > 0.0f) - (d < 0.0f);
        d = cur0.z - prev0.z; s2 += (d > 0.0f) - (d < 0.0f);
        d = cur0.w - prev0.w; s3 += (d > 0.0f) - (d < 0.0f);
        d = cur1.x - prev1.x; s4 += (d > 0.0f) - (d < 0.0f);
        d = cur1.y - prev1.y; s5 += (d > 0.0f) - (d < 0.0f);
        d = cur1.z - prev1.z; s6 += (d > 0.0f) - (d < 0.0f);
        d = cur1.w - prev1.w; s7 += (d > 0.0f) - (d < 0.0f);
        prev0 = cur0;
        prev1 = cur1;
    }

    const float f0 = (float)s0, f1 = (float)s1, f2 = (float)s2, f3 = (float)s3;
    const float f4 = (float)s4, f5 = (float)s5, f6 = (float)s6, f7 = (float)s7;

    // Fused FC: per-thread dot over its 8 k's. Wfc (160KB) stays L2-resident
    // (x loads are nontemporal, no-allocate).
    float acc[NUM_CLASSES];
#pragma unroll
    for (int c = 0; c < NUM_CLASSES; ++c) {
        const float* wr = Wfc + (size_t)c * K_ + kbase;
        const float4 w0 = *reinterpret_cast<const float4*>(wr);
        const float4 w1 = *reinterpret_cast<const float4*>(wr + 2048);
        acc[c] = f0 * w0.x + f1 * w0.y + f2 * w0.z + f3 * w0.w
               + f4 * w1.x + f5 * w1.y + f6 * w1.z + f7 * w1.w;
    }

    // Wave-shuffle reduce (fixed order, deterministic), then 8-wave combine.
#pragma unroll
    for (int off = 32; off > 0; off >>= 1) {
#pragma unroll
        for (int c = 0; c < NUM_CLASSES; ++c)
            acc[c] += __shfl_down(acc[c], off, 64);
    }

    __shared__ float red[NUM_CLASSES][NWAVES_];
    const int wave = tid >> 6;
    const int lane = tid & 63;
    if (lane == 0) {
#pragma unroll
        for (int c = 0; c < NUM_CLASSES; ++c) red[c][wave] = acc[c];
    }
    __syncthreads();

    // Publish 10 partials; release-fence; take tickets. The thread whose
    // ticket is the global last marks this block as the finisher.
    if (tid < NUM_CLASSES) {
        float v = 0.0f;
#pragma unroll
        for (int w = 0; w < NWAVES_; ++w) v += red[tid][w];
        P[((size_t)b * NUM_CLASSES + tid) * NPART_ + tc] = v;
        __threadfence();                       // device-scope release
        const unsigned old = atomicAdd(cnt, 1u);
        if (old == (unsigned)(NTICKETS_ - 1)) sh_last = 1;
    }
    __syncthreads();

    if (sh_last) {
        __threadfence();                       // device-scope acquire
        // Fixed-order final sum -> bit-deterministic output.
        for (int idx = tid; idx < B_ * NUM_CLASSES; idx += THREADS_) {
            const int c = idx % NUM_CLASSES;
            const float* p = P + (size_t)idx * NPART_;
            float s = 0.0f;
#pragma unroll
            for (int i = 0; i < NPART_; ++i) s += p[i];
            out[idx] = (s + (float)(TS_ - 1) * bfc[c]) * (1.0f / (float)TS_);
        }
    }
}

extern "C" void kernel_launch(void* const* d_in, const int* in_sizes, int n_in,
                              void* d_out, int out_size, void* d_ws, size_t ws_size,
                              hipStream_t stream)
{
    const float* x   = (const float*)d_in[0];
    const float* Wfc = (const float*)d_in[1];
    const float* bfc = (const float*)d_in[2];
    float* out = (float*)d_out;

    float* P = (float*)d_ws;                               // 20 KiB
    unsigned int* cnt = (unsigned int*)((char*)d_ws + B_ * NUM_CLASSES * NPART_ * sizeof(float));

    // Reset ticket counter each call (graph-capturable async memset).
    (void)hipMemsetAsync(cnt, 0, sizeof(unsigned int), stream);

    dim3 grid(B_, TCHUNKS_);
    sign_fc_fused_kernel<<<grid, THREADS_, 0, stream>>>(x, Wfc, bfc, out, P, cnt);
}

// Round 8
// 44.423 us; speedup vs baseline: 1.0564x; 1.0564x over previous
//
#include <hip/hip_runtime.h>

#ifndef NUM_CLASSES
#define NUM_CLASSES 10
#endif

// x: (B=64, TS=128, C=1, H=64, W=64) fp32 -> K = 4096
// Derivation: with F_THRESH=0, h_t == frame_{t-1} exactly, so
//   out[b,c] = ( sum_k Wfc[c,k] * S[b,k] + (TS-1)*bfc[c] ) / TS,
//   S[b,k]   = sum_{t=1..TS-1} sign3(x[b,t,k] - x[b,t-1,k])
// R8 = R5 streaming kernel (plain float4 loads -- R7's nontemporal loads
// regressed 16us) + single-kernel fusion via last-block-done ticket with
// ONE atomic per block (R7 used 10/block = 5120 same-address atomics;
// Guideline 12). Block (b,tc) streams 17 full 16KB frames contiguously;
// FC fused per-thread; last-retiring block does the fixed-order final sum.
constexpr int B_        = 64;
constexpr int TS_       = 128;
constexpr int K_        = 4096;
constexpr int THREADS_  = 512;
constexpr int TCHUNKS_  = 8;
constexpr int TSTEP_    = 16;                      // diffs per chunk (last: 15)
constexpr int NPART_    = TCHUNKS_;                // 8 partials per (b,c)
constexpr int NWAVES_   = THREADS_ / 64;           // 8
constexpr int NBLOCKS_  = B_ * TCHUNKS_;           // 512

// Grid: (B_, TCHUNKS_) = 512 blocks, block: 512.
__global__ __launch_bounds__(THREADS_) void sign_fc_fused_kernel(
    const float* __restrict__ x, const float* __restrict__ Wfc,
    const float* __restrict__ bfc, float* __restrict__ out,
    float* __restrict__ P, unsigned int* __restrict__ cnt)
{
    const int b   = blockIdx.x;
    const int tc  = blockIdx.y;
    const int tid = threadIdx.x;

    __shared__ int sh_last;

    const int t_begin = tc * TSTEP_;
    const int t_end   = (tc == TCHUNKS_ - 1) ? (TS_ - 1) : (t_begin + TSTEP_);

    // Thread owns 8 k's: tid*4 + {0..3} and 2048 + tid*4 + {0..3}.
    const int kbase = tid * 4;

    const float* xp = x + ((size_t)b * TS_ + t_begin) * K_ + kbase;
    float4 prev0 = *reinterpret_cast<const float4*>(xp);
    float4 prev1 = *reinterpret_cast<const float4*>(xp + 2048);

    int s0 = 0, s1 = 0, s2 = 0, s3 = 0, s4 = 0, s5 = 0, s6 = 0, s7 = 0;

#pragma unroll 4
    for (int t = t_begin + 1; t <= t_end; ++t) {
        xp += K_;
        const float4 cur0 = *reinterpret_cast<const float4*>(xp);
        const float4 cur1 = *reinterpret_cast<const float4*>(xp + 2048);
        float d;
        d = cur0.x - prev0.x; s0 += (d > 0.0f) - (d < 0.0f);
        d = cur0.y - prev0.y; s1 += (d > 0.0f) - (d < 0.0f);
        d = cur0.z - prev0.z; s2 += (d > 0.0f) - (d < 0.0f);
        d = cur0.w - prev0.w; s3 += (d > 0.0f) - (d < 0.0f);
        d = cur1.x - prev1.x; s4 += (d > 0.0f) - (d < 0.0f);
        d = cur1.y - prev1.y; s5 += (d > 0.0f) - (d < 0.0f);
        d = cur1.z - prev1.z; s6 += (d > 0.0f) - (d < 0.0f);
        d = cur1.w - prev1.w; s7 += (d > 0.0f) - (d < 0.0f);
        prev0 = cur0;
        prev1 = cur1;
    }

    const float f0 = (float)s0, f1 = (float)s1, f2 = (float)s2, f3 = (float)s3;
    const float f4 = (float)s4, f5 = (float)s5, f6 = (float)s6, f7 = (float)s7;

    // Fused FC: per-thread dot over its 8 k's. Wfc (160KB) is L2/L3-resident.
    float acc[NUM_CLASSES];
#pragma unroll
    for (int c = 0; c < NUM_CLASSES; ++c) {
        const float* wr = Wfc + (size_t)c * K_ + kbase;
        const float4 w0 = *reinterpret_cast<const float4*>(wr);
        const float4 w1 = *reinterpret_cast<const float4*>(wr + 2048);
        acc[c] = f0 * w0.x + f1 * w0.y + f2 * w0.z + f3 * w0.w
               + f4 * w1.x + f5 * w1.y + f6 * w1.z + f7 * w1.w;
    }

    // Wave-shuffle reduce (fixed order, deterministic), then 8-wave combine.
#pragma unroll
    for (int off = 32; off > 0; off >>= 1) {
#pragma unroll
        for (int c = 0; c < NUM_CLASSES; ++c)
            acc[c] += __shfl_down(acc[c], off, 64);
    }

    __shared__ float red[NUM_CLASSES][NWAVES_];
    const int wave = tid >> 6;
    const int lane = tid & 63;
    if (lane == 0) {
#pragma unroll
        for (int c = 0; c < NUM_CLASSES; ++c) red[c][wave] = acc[c];
    }
    __syncthreads();

    // Publish 10 partials, release-fence, then ONE ticket per block.
    if (tid < NUM_CLASSES) {
        float v = 0.0f;
#pragma unroll
        for (int w = 0; w < NWAVES_; ++w) v += red[tid][w];
        P[((size_t)b * NUM_CLASSES + tid) * NPART_ + tc] = v;
        __threadfence();                       // device-scope release
    }
    __syncthreads();                           // P writes + fences done block-wide

    if (tid == 0) {
        const unsigned old = atomicAdd(cnt, 1u);
        sh_last = (old == (unsigned)(NBLOCKS_ - 1)) ? 1 : 0;
    }
    __syncthreads();

    if (sh_last) {
        __threadfence();                       // device-scope acquire
        // Fixed-order final sum -> bit-deterministic output.
        for (int idx = tid; idx < B_ * NUM_CLASSES; idx += THREADS_) {
            const int c = idx % NUM_CLASSES;
            const float* p = P + (size_t)idx * NPART_;
            float s = 0.0f;
#pragma unroll
            for (int i = 0; i < NPART_; ++i) s += p[i];
            out[idx] = (s + (float)(TS_ - 1) * bfc[c]) * (1.0f / (float)TS_);
        }
    }
}

extern "C" void kernel_launch(void* const* d_in, const int* in_sizes, int n_in,
                              void* d_out, int out_size, void* d_ws, size_t ws_size,
                              hipStream_t stream)
{
    const float* x   = (const float*)d_in[0];
    const float* Wfc = (const float*)d_in[1];
    const float* bfc = (const float*)d_in[2];
    float* out = (float*)d_out;

    float* P = (float*)d_ws;                               // 20 KiB
    unsigned int* cnt = (unsigned int*)((char*)d_ws + B_ * NUM_CLASSES * NPART_ * sizeof(float));

    // Reset ticket counter each call (graph-capturable async memset).
    (void)hipMemsetAsync(cnt, 0, sizeof(unsigned int), stream);

    dim3 grid(B_, TCHUNKS_);
    sign_fc_fused_kernel<<<grid, THREADS_, 0, stream>>>(x, Wfc, bfc, out, P, cnt);
}

// Round 9
// 35.071 us; speedup vs baseline: 1.3381x; 1.2667x over previous
//
#include <hip/hip_runtime.h>

#ifndef NUM_CLASSES
#define NUM_CLASSES 10
#endif

// x: (B=64, TS=128, C=1, H=64, W=64) fp32 -> K = 4096
// Derivation: with F_THRESH=0, h_t == frame_{t-1} exactly, so
//   out[b,c] = ( sum_k Wfc[c,k] * S[b,k] + (TS-1)*bfc[c] ) / TS,
//   S[b,k]   = sum_{t=1..TS-1} sign3(x[b,t,k] - x[b,t-1,k])
// R9 = R5 layout (block (b,tc) streams 17 full 16KB frames contiguously;
// two kernels -- R7/R8 proved single-kernel fusion costs ~14us in
// device-scope atomic/fence overhead) with 1024-thread blocks:
// thread owns ONE float4, 512 blocks = 2/CU -> 32 waves/CU (was 16),
// and the per-thread FC epilogue halves (10 Wfc loads vs 20).
constexpr int B_        = 64;
constexpr int TS_       = 128;
constexpr int K_        = 4096;
constexpr int THREADS_  = 1024;
constexpr int TCHUNKS_  = 8;
constexpr int TSTEP_    = 16;                      // diffs per chunk (last: 15)
constexpr int NPART_    = TCHUNKS_;                // 8 partials per (b,c)
constexpr int NWAVES_   = THREADS_ / 64;           // 16

// Kernel 1: per-(b,tc) block: stream full frames, accumulate sign3 per k,
// fused FC -> 10 partial logits.
// Grid: (B_, TCHUNKS_) = 512 blocks, block: 1024.
__global__ __launch_bounds__(THREADS_) void sign_fc_kernel(
    const float* __restrict__ x, const float* __restrict__ Wfc,
    float* __restrict__ P)
{
    const int b   = blockIdx.x;
    const int tc  = blockIdx.y;
    const int tid = threadIdx.x;

    const int t_begin = tc * TSTEP_;
    const int t_end   = (tc == TCHUNKS_ - 1) ? (TS_ - 1) : (t_begin + TSTEP_);

    // Thread owns 4 consecutive k's: tid*4 + {0..3}. 1024 thr * 4 = K.
    const int kbase = tid * 4;

    const float* xp = x + ((size_t)b * TS_ + t_begin) * K_ + kbase;
    float4 prev = *reinterpret_cast<const float4*>(xp);

    int s0 = 0, s1 = 0, s2 = 0, s3 = 0;

#pragma unroll 4
    for (int t = t_begin + 1; t <= t_end; ++t) {
        xp += K_;
        const float4 cur = *reinterpret_cast<const float4*>(xp);
        float d;
        d = cur.x - prev.x; s0 += (d > 0.0f) - (d < 0.0f);
        d = cur.y - prev.y; s1 += (d > 0.0f) - (d < 0.0f);
        d = cur.z - prev.z; s2 += (d > 0.0f) - (d < 0.0f);
        d = cur.w - prev.w; s3 += (d > 0.0f) - (d < 0.0f);
        prev = cur;
    }

    const float f0 = (float)s0, f1 = (float)s1, f2 = (float)s2, f3 = (float)s3;

    // Fused FC: per-thread dot over its 4 k's. Wfc (160KB) is L2/L3-resident.
    float acc[NUM_CLASSES];
#pragma unroll
    for (int c = 0; c < NUM_CLASSES; ++c) {
        const float4 w = *reinterpret_cast<const float4*>(Wfc + (size_t)c * K_ + kbase);
        acc[c] = f0 * w.x + f1 * w.y + f2 * w.z + f3 * w.w;
    }

    // Wave-shuffle reduce (fixed order, deterministic), then 16-wave combine.
#pragma unroll
    for (int off = 32; off > 0; off >>= 1) {
#pragma unroll
        for (int c = 0; c < NUM_CLASSES; ++c)
            acc[c] += __shfl_down(acc[c], off, 64);
    }

    __shared__ float red[NUM_CLASSES][NWAVES_];
    const int wave = tid >> 6;
    const int lane = tid & 63;
    if (lane == 0) {
#pragma unroll
        for (int c = 0; c < NUM_CLASSES; ++c) red[c][wave] = acc[c];
    }
    __syncthreads();

    if (tid < NUM_CLASSES) {
        float v = 0.0f;
#pragma unroll
        for (int w = 0; w < NWAVES_; ++w) v += red[tid][w];
        P[((size_t)b * NUM_CLASSES + tid) * NPART_ + tc] = v;
    }
}

// Kernel 2: out[b][c] = (sum_{i<8} P[b][c][i] + (TS-1)*bfc[c]) / TS
// Grid: B_, block: 64. Fixed-order -> bit-deterministic.
__global__ __launch_bounds__(64) void fc_finish_kernel(
    const float* __restrict__ P, const float* __restrict__ bfc,
    float* __restrict__ out)
{
    const int b = blockIdx.x;
    const int c = threadIdx.x;
    if (c >= NUM_CLASSES) return;

    const float* p = P + ((size_t)b * NUM_CLASSES + c) * NPART_;
    float s = 0.0f;
#pragma unroll
    for (int i = 0; i < NPART_; ++i) s += p[i];

    out[b * NUM_CLASSES + c] = (s + (float)(TS_ - 1) * bfc[c]) * (1.0f / (float)TS_);
}

extern "C" void kernel_launch(void* const* d_in, const int* in_sizes, int n_in,
                              void* d_out, int out_size, void* d_ws, size_t ws_size,
                              hipStream_t stream)
{
    const float* x   = (const float*)d_in[0];
    const float* Wfc = (const float*)d_in[1];
    const float* bfc = (const float*)d_in[2];
    float* out = (float*)d_out;
    float* P = (float*)d_ws;   // needs B_*NUM_CLASSES*NPART_*4 = 20 KiB

    dim3 grid1(B_, TCHUNKS_);
    sign_fc_kernel<<<grid1, THREADS_, 0, stream>>>(x, Wfc, P);

    fc_finish_kernel<<<B_, 64, 0, stream>>>(P, bfc, out);
}

// Round 10
// 33.523 us; speedup vs baseline: 1.3999x; 1.0462x over previous
//
#include <hip/hip_runtime.h>

#ifndef NUM_CLASSES
#define NUM_CLASSES 10
#endif

// x: (B=64, TS=128, C=1, H=64, W=64) fp32 -> K = 4096
// Derivation: with F_THRESH=0, h_t == frame_{t-1} exactly, so
//   out[b,c] = ( sum_k Wfc[c,k] * S[b,k] + (TS-1)*bfc[c] ) / TS,
//   S[b,k]   = sum_{t=1..TS-1} sign3(x[b,t,k] - x[b,t-1,k])
// R10 = R5 streaming core (block (b,tc) streams 17 full 16KB frames
// contiguously; 512x512; best measured: 30.15us) with the finish kernel
// replaced by distributed atomicAdd into out: 5120 atomics over 640
// DISTINCT addresses (~8/addr -- R8's regression was same-address tickets
// + device-scope fences, neither present here; no fence needed since the
// atomic value itself is the communication). d_out is zeroed by a leading
// hipMemsetAsync node (cheaper than the ~3-4us dependent finish dispatch).
constexpr int B_        = 64;
constexpr int TS_       = 128;
constexpr int K_        = 4096;
constexpr int THREADS_  = 512;
constexpr int TCHUNKS_  = 8;
constexpr int TSTEP_    = 16;                      // diffs per chunk (last: 15)
constexpr int NWAVES_   = THREADS_ / 64;           // 8

// Grid: (B_, TCHUNKS_) = 512 blocks, block: 512.
__global__ __launch_bounds__(THREADS_) void sign_fc_atomic_kernel(
    const float* __restrict__ x, const float* __restrict__ Wfc,
    const float* __restrict__ bfc, float* __restrict__ out)
{
    const int b   = blockIdx.x;
    const int tc  = blockIdx.y;
    const int tid = threadIdx.x;

    const int t_begin = tc * TSTEP_;
    const int t_end   = (tc == TCHUNKS_ - 1) ? (TS_ - 1) : (t_begin + TSTEP_);

    // Thread owns 8 k's: tid*4 + {0..3} and 2048 + tid*4 + {0..3}.
    const int kbase = tid * 4;

    const float* xp = x + ((size_t)b * TS_ + t_begin) * K_ + kbase;
    float4 prev0 = *reinterpret_cast<const float4*>(xp);
    float4 prev1 = *reinterpret_cast<const float4*>(xp + 2048);

    int s0 = 0, s1 = 0, s2 = 0, s3 = 0, s4 = 0, s5 = 0, s6 = 0, s7 = 0;

#pragma unroll 4
    for (int t = t_begin + 1; t <= t_end; ++t) {
        xp += K_;
        const float4 cur0 = *reinterpret_cast<const float4*>(xp);
        const float4 cur1 = *reinterpret_cast<const float4*>(xp + 2048);
        float d;
        d = cur0.x - prev0.x; s0 += (d > 0.0f) - (d < 0.0f);
        d = cur0.y - prev0.y; s1 += (d > 0.0f) - (d < 0.0f);
        d = cur0.z - prev0.z; s2 += (d > 0.0f) - (d < 0.0f);
        d = cur0.w - prev0.w; s3 += (d > 0.0f) - (d < 0.0f);
        d = cur1.x - prev1.x; s4 += (d > 0.0f) - (d < 0.0f);
        d = cur1.y - prev1.y; s5 += (d > 0.0f) - (d < 0.0f);
        d = cur1.z - prev1.z; s6 += (d > 0.0f) - (d < 0.0f);
        d = cur1.w - prev1.w; s7 += (d > 0.0f) - (d < 0.0f);
        prev0 = cur0;
        prev1 = cur1;
    }

    const float f0 = (float)s0, f1 = (float)s1, f2 = (float)s2, f3 = (float)s3;
    const float f4 = (float)s4, f5 = (float)s5, f6 = (float)s6, f7 = (float)s7;

    // Fused FC: per-thread dot over its 8 k's. Wfc (160KB) is L2/L3-resident.
    float acc[NUM_CLASSES];
#pragma unroll
    for (int c = 0; c < NUM_CLASSES; ++c) {
        const float* wr = Wfc + (size_t)c * K_ + kbase;
        const float4 w0 = *reinterpret_cast<const float4*>(wr);
        const float4 w1 = *reinterpret_cast<const float4*>(wr + 2048);
        acc[c] = f0 * w0.x + f1 * w0.y + f2 * w0.z + f3 * w0.w
               + f4 * w1.x + f5 * w1.y + f6 * w1.z + f7 * w1.w;
    }

    // Wave-shuffle reduce (fixed order), then 8-wave combine.
#pragma unroll
    for (int off = 32; off > 0; off >>= 1) {
#pragma unroll
        for (int c = 0; c < NUM_CLASSES; ++c)
            acc[c] += __shfl_down(acc[c], off, 64);
    }

    __shared__ float red[NUM_CLASSES][NWAVES_];
    const int wave = tid >> 6;
    const int lane = tid & 63;
    if (lane == 0) {
#pragma unroll
        for (int c = 0; c < NUM_CLASSES; ++c) red[c][wave] = acc[c];
    }
    __syncthreads();

    // One atomicAdd per (block, class): 8 adds per output address total.
    if (tid < NUM_CLASSES) {
        float v = 0.0f;
#pragma unroll
        for (int w = 0; w < NWAVES_; ++w) v += red[tid][w];
        v *= (1.0f / (float)TS_);
        if (tc == 0) v += ((float)(TS_ - 1) / (float)TS_) * bfc[tid];
        atomicAdd(&out[b * NUM_CLASSES + tid], v);
    }
}

extern "C" void kernel_launch(void* const* d_in, const int* in_sizes, int n_in,
                              void* d_out, int out_size, void* d_ws, size_t ws_size,
                              hipStream_t stream)
{
    const float* x   = (const float*)d_in[0];
    const float* Wfc = (const float*)d_in[1];
    const float* bfc = (const float*)d_in[2];
    float* out = (float*)d_out;

    // Zero the accumulator each call (graph-capturable async memset).
    (void)hipMemsetAsync(out, 0, (size_t)out_size * sizeof(float), stream);

    dim3 grid(B_, TCHUNKS_);
    sign_fc_atomic_kernel<<<grid, THREADS_, 0, stream>>>(x, Wfc, bfc, out);
}